// Round 7
// baseline (284.588 us; speedup 1.0000x reference)
//
#include <hip/hip_runtime.h>
#include <hip/hip_fp16.h>

typedef _Float16 f16;
typedef f16 f16x4 __attribute__((ext_vector_type(4)));
typedef f16 f16x8 __attribute__((ext_vector_type(8)));
typedef float f32x4 __attribute__((ext_vector_type(4)));

#define NTOK 32768   // B*S
#define KDIM 512
#define SLEN 4096
#define BATCH 8
#define WSZ  262144  // 512*512

// rcp-based tanh: (1-t)*rcp(1+t) instead of fdiv (~half the VALU ops).
// v_rcp_f32 is ~1 ULP(22b) — invisible after the f16 round of the h write-back.
__device__ __forceinline__ float fast_tanh(float x) {
    float ax = fabsf(x);
    float t = __expf(-2.0f * ax);
    float r = (1.0f - t) * __builtin_amdgcn_rcpf(1.0f + t);
    return copysignf(r, x);
}

// ---------------- chain inner-loop helpers (8-wave, 64 feat/wave) ----------------
__device__ __forceinline__ void load_wf(f16x8 (&wf)[4], const f16* __restrict__ wp,
                                        int j0w, int fr, int col)
{
    #pragma unroll
    for (int jt = 0; jt < 4; ++jt)
        wf[jt] = *(const f16x8*)&wp[(size_t)(j0w + jt * 16 + fr) * KDIM + col];
}

__device__ __forceinline__ void load_hf4(f16x8 (&hf)[4], const f16 (*hbuf)[512],
                                         int kt, int fr, int q, int mt0)
{
    #pragma unroll
    for (int i = 0; i < 4; ++i) {
        const int m = (mt0 + i) * 16 + fr;
        const int c = (kt * 4 + q) ^ (m & 7);
        hf[i] = *(const f16x8*)&hbuf[m][c << 3];
    }
}

__device__ __forceinline__ void mfma16(f32x4 (&acc)[4][8], const f16x8 (&wf)[4],
                                       const f16x8 (&hf)[4], int mt0)
{
    __builtin_amdgcn_s_setprio(1);
    #pragma unroll
    for (int jt = 0; jt < 4; ++jt)
        #pragma unroll
        for (int i = 0; i < 4; ++i)
            acc[jt][mt0 + i] = __builtin_amdgcn_mfma_f32_16x16x32_f16(
                wf[jt], hf[i], acc[jt][mt0 + i], 0, 0, 0);
    __builtin_amdgcn_s_setprio(0);
}

// Fully pipelined kt loop: BOTH the weight fragments (wfA/wfB ping-pong, one kt
// ahead) and the LDS h fragments (hfP/hfQ ping-pong, one HALF-step ahead) are
// issued before the MFMAs that consume them — ds_read latency (~120cy) hides
// under the previous 16-MFMA block, global latency under a full kt. All
// prefetch columns wrap &15 (the tail prefetch re-reads kt=0: cached, no
// over-fetch — round-5's dead +2KB prefetch cost ~4MB of FETCH).
__device__ __forceinline__ void gemm_ktloop(f32x4 (&acc)[4][8], const f16 (*hbuf)[512],
                                            const f16* __restrict__ wp, f16x8 (&wfA)[4],
                                            int j0w, int fr, int q)
{
    f16x8 wfB[4], hfP[4], hfQ[4];
    load_hf4(hfP, hbuf, 0, fr, q, 0);                      // kt0 lo
    #pragma unroll
    for (int kt = 0; kt < 16; kt += 2) {
        load_wf(wfB, wp, j0w, fr, ((kt + 1) & 15) * 32 + q * 8);
        load_hf4(hfQ, hbuf, kt, fr, q, 4);                 // kt hi
        mfma16(acc, wfA, hfP, 0);                          // kt lo
        load_hf4(hfP, hbuf, (kt + 1) & 15, fr, q, 0);      // kt+1 lo
        mfma16(acc, wfA, hfQ, 4);                          // kt hi
        load_wf(wfA, wp, j0w, fr, ((kt + 2) & 15) * 32 + q * 8);
        load_hf4(hfQ, hbuf, (kt + 1) & 15, fr, q, 4);      // kt+1 hi
        mfma16(acc, wfB, hfP, 0);                          // kt+1 lo
        load_hf4(hfP, hbuf, (kt + 2) & 15, fr, q, 0);      // kt+2 lo
        mfma16(acc, wfB, hfQ, 4);                          // kt+1 hi
    }
}

// =====================  fused 4-phase chain (proven geometry)  =====================
// Each block owns 128 tokens. LDS holds h (or X) as [token 128][feature 512] f16,
// XOR-swizzled in 16B chunks: element (m, f) lives at m*512 + ((f>>3 ^ (m&7))<<3) + (f&7).
// GEOMETRY IS LOAD-BEARING: 128 tokens/block, 8 waves, 64 features/wave.
// Round-3 (64 tok/block) and round-6 (16 waves x 32 feat) both exploded HBM
// traffic (FETCH 41->164 / 45->134 MB) and regressed ~25%.
__global__ __launch_bounds__(512, 2)
void chain_kernel(const float* __restrict__ xs,
                  const f16*  __restrict__ Wp,    // [4][512*512] f16 row-major [j][k]
                  const float* __restrict__ bias, // [4][512] fp32
                  float* __restrict__ out)        // y2 [S,B,512] then hs [8*512]
{
    __shared__ f16 hbuf[128][512];   // 128 KB

    const int tid  = threadIdx.x;
    const int bid  = blockIdx.x;
    const int n0   = bid * 128;
    const int lane = tid & 63;
    const int wave = tid >> 6;       // 0..7: wave owns features [wave*64, +64)
    const int fr   = lane & 15;      // token within 16-tile (D^T col)
    const int q    = lane >> 4;      // 0..3
    const int j0w  = wave * 64;

    // ---- stage X tile: fp32 -> f16 into hbuf (swizzled) ----
    {
        const int tk = tid >> 2;                 // 0..127
        const int cq = tid & 3;                  // 0..3
        const float* __restrict__ src = &xs[(size_t)(n0 + tk) * KDIM];
        #pragma unroll
        for (int kt = 0; kt < 16; ++kt) {
            const int k = kt * 32 + cq * 8;
            const float4 v0 = *(const float4*)&src[k];
            const float4 v1 = *(const float4*)&src[k + 4];
            f16x8 h;
            h[0]=(f16)v0.x; h[1]=(f16)v0.y; h[2]=(f16)v0.z; h[3]=(f16)v0.w;
            h[4]=(f16)v1.x; h[5]=(f16)v1.y; h[6]=(f16)v1.z; h[7]=(f16)v1.w;
            const int c = (k >> 3) ^ (tk & 7);
            *(f16x8*)&hbuf[tk][c << 3] = h;
        }
    }

    f32x4 acc[4][8];   // [jt][mt] : 128 AGPRs

    // ---- phases 0..2: h = tanh(h_prev @ W^T + b), in-place in LDS ----
    for (int ph = 0; ph < 3; ++ph) {
        const f16*   __restrict__ wp = Wp + (size_t)ph * WSZ;
        const float* __restrict__ bp = bias + ph * KDIM;

        f16x8 wfA[4];
        load_wf(wfA, wp, j0w, fr, q * 8);   // kt=0 prefetch, before the barrier

        f32x4 bv[4];
        #pragma unroll
        for (int jt = 0; jt < 4; ++jt)
            bv[jt] = *(const f32x4*)&bp[j0w + jt * 16 + q * 4];
        #pragma unroll
        for (int jt = 0; jt < 4; ++jt)
            #pragma unroll
            for (int mt = 0; mt < 8; ++mt)
                acc[jt][mt] = bv[jt];

        __syncthreads();   // h (or X) writes visible before reads

        gemm_ktloop(acc, hbuf, wp, wfA, j0w, fr, q);

        __syncthreads();   // all reads done before overwrite

        #pragma unroll
        for (int jt = 0; jt < 4; ++jt) {
            const int j0f  = j0w + jt * 16 + q * 4;   // 4 consecutive features
            const int c    = j0f >> 3;
            const int half = j0f & 7;                 // 0 or 4
            #pragma unroll
            for (int mt = 0; mt < 8; ++mt) {
                const int m = mt * 16 + fr;
                f16x4 hv;
                hv[0] = (f16)fast_tanh(acc[jt][mt][0]);
                hv[1] = (f16)fast_tanh(acc[jt][mt][1]);
                hv[2] = (f16)fast_tanh(acc[jt][mt][2]);
                hv[3] = (f16)fast_tanh(acc[jt][mt][3]);
                *(f16x4*)&hbuf[m][((c ^ (m & 7)) << 3) + half] = hv;
            }
        }
    }

    // ---- phase 3: y2 = h2 @ W_hy1^T + b -> global (D^T layout matches [s,b,j]) ----
    {
        const f16*   __restrict__ wp = Wp + (size_t)3 * WSZ;
        const float* __restrict__ bp = bias + 3 * KDIM;

        f16x8 wfA[4];
        load_wf(wfA, wp, j0w, fr, q * 8);   // kt=0 prefetch

        f32x4 bv[4];
        #pragma unroll
        for (int jt = 0; jt < 4; ++jt)
            bv[jt] = *(const f32x4*)&bp[j0w + jt * 16 + q * 4];
        #pragma unroll
        for (int jt = 0; jt < 4; ++jt)
            #pragma unroll
            for (int mt = 0; mt < 8; ++mt)
                acc[jt][mt] = bv[jt];

        __syncthreads();   // h2 writes visible

        // hs_final: blocks holding token s==4095 (bid = 32b+31, local token 127)
        if ((bid & 31) == 31) {
            const int f = tid;                      // feature 0..511
            const int c = (f >> 3) ^ 7;             // m=127 -> m&7 = 7
            out[(size_t)SLEN * BATCH * KDIM + (size_t)(bid >> 5) * KDIM + f] =
                (float)hbuf[127][(c << 3) + (f & 7)];
        }

        gemm_ktloop(acc, hbuf, wp, wfA, j0w, fr, q);

        #pragma unroll
        for (int jt = 0; jt < 4; ++jt) {
            const int j = j0w + jt * 16 + q * 4;
            #pragma unroll
            for (int mt = 0; mt < 8; ++mt) {
                const int n  = n0 + mt * 16 + fr;
                const int s  = n & (SLEN - 1);
                const int bb = n >> 12;
                *(f32x4*)&out[(size_t)(s * BATCH + bb) * KDIM + j] = acc[jt][mt];
            }
        }
    }
}

// ============================================================================
// prep_mega: ONE kernel for everything before the chain (unchanged, verified).
//   blocks [0,128)    : cvt W_xh0 (fp32->f16)     -> Wp[0]
//   blocks [128,256)  : cvt W_hy_h[1] (fp32->f16) -> Wp[3]
//   blocks [256,272)  : bias matvec rows 1..2
//   block  272        : trivial bias rows 0,3
//   blocks [273,305)  : fold GEMMs FROM RAW fp32:
//       Wp[1+li] = W_hh_h[li] + W_xh_h[li] @ W_hy_prev   (f16 out)
// ============================================================================
__device__ __forceinline__ void cvt2048(const float* __restrict__ src, f16* __restrict__ dst, int t)
{
    const float4 v0 = *(const float4*)&src[(size_t)t * 8];
    const float4 v1 = *(const float4*)&src[(size_t)t * 8 + 4];
    f16x8 h;
    h[0]=(f16)v0.x; h[1]=(f16)v0.y; h[2]=(f16)v0.z; h[3]=(f16)v0.w;
    h[4]=(f16)v1.x; h[5]=(f16)v1.y; h[6]=(f16)v1.z; h[7]=(f16)v1.w;
    *(f16x8*)&dst[(size_t)t * 8] = h;
}

__global__ __launch_bounds__(256)
void prep_mega(const float* __restrict__ W_xh0, const float* __restrict__ W_xh_h,
               const float* __restrict__ W_hh_h, const float* __restrict__ W_hy0,
               const float* __restrict__ W_hy_h,
               const float* __restrict__ b_xh0, const float* __restrict__ b_hh0,
               const float* __restrict__ b_xh_h, const float* __restrict__ b_hh_h,
               const float* __restrict__ b_hy0, const float* __restrict__ b_hy_h,
               f16* __restrict__ Wp, float* __restrict__ bias)
{
    __shared__ f16 A_s[128][64];   // 16 KB
    __shared__ f16 B_s[128][64];   // 16 KB

    const int b = blockIdx.x, tid = threadIdx.x;
    const int lane = tid & 63, wave = tid >> 6;

    if (b < 128) { cvt2048(W_xh0, Wp, b * 256 + tid); return; }
    if (b < 256) { cvt2048(W_hy_h + WSZ, Wp + 3 * WSZ, (b - 128) * 256 + tid); return; }

    if (b < 272) {
        // bias rows 1..2: bias[1+li][j] = b_hh + b_xh + W_xh_h[li][j,:] . b_hy_prev
        const int bb = b - 256;                   // 0..15
        const int li = bb >> 3;                   // 0..1
        const int j0 = (bb & 7) * 64 + wave * 16;
        const float* __restrict__ W  = W_xh_h + (size_t)li * WSZ;
        const float* __restrict__ bh = li ? b_hy_h : b_hy0;
        const float4 h0 = *(const float4*)&bh[lane * 8];
        const float4 h1 = *(const float4*)&bh[lane * 8 + 4];
        for (int jj = 0; jj < 16; ++jj) {
            const int j = j0 + jj;
            const float4 w0 = *(const float4*)&W[(size_t)j * 512 + lane * 8];
            const float4 w1 = *(const float4*)&W[(size_t)j * 512 + lane * 8 + 4];
            float s = w0.x*h0.x + w0.y*h0.y + w0.z*h0.z + w0.w*h0.w
                    + w1.x*h1.x + w1.y*h1.y + w1.z*h1.z + w1.w*h1.w;
            #pragma unroll
            for (int off = 32; off; off >>= 1) s += __shfl_xor(s, off, 64);
            if (lane == 0)
                bias[(1 + li) * KDIM + j] =
                    b_hh_h[li * KDIM + j] + b_xh_h[li * KDIM + j] + s;
        }
        return;
    }

    if (b == 272) {
        // bias rows 0 and 3 (trivial elementwise), 256 threads x 2 j
        #pragma unroll
        for (int u = 0; u < 2; ++u) {
            const int j = u * 256 + tid;
            bias[j] = b_xh0[j] + b_hh0[j];
            bias[3 * KDIM + j] = b_hy_h[KDIM + j];
        }
        return;
    }

    // ---- fold GEMM from raw fp32: Wp[1+li] = W_hh_h[li] + W_xh_h[li] @ W_hy_prev ----
    {
        const int fb   = b - 273;                 // 0..31
        const int fold = fb >> 4;                 // 0..1 (= li)
        const int bid  = fb & 15;
        const float* __restrict__ A    = W_xh_h + (size_t)fold * WSZ;  // [n][k] fp32
        const float* __restrict__ Why  = fold ? W_hy_h : W_hy0;        // [k][j] fp32
        const float* __restrict__ Cadd = W_hh_h + (size_t)fold * WSZ;
        f16*         __restrict__ Cp   = Wp + WSZ + (size_t)fold * WSZ;

        const int n0 = (bid >> 2) * 128;
        const int j0 = (bid & 3) * 128;

        const int wm = wave >> 1, wn = wave & 1;
        const int fr = lane & 15, q = lane >> 4, sw = fr & 7;

        // staging thread mapping
        const int ar  = tid >> 1;                 // row 0..127 (A stage)
        const int ac0 = (tid & 1) * 4;            // chunk base 0 or 4
        const int bk  = tid >> 2;                 // k 0..63 (B stage)
        const int bjq = tid & 3;                  // j quarter (32 j each)

        f32x4 acc[4][4] = {};

        for (int kt = 0; kt < 8; ++kt) {
            const int k0 = kt * 64;
            __syncthreads();   // previous reads done before overwrite
            // A_s[r][k] = (f16)A[n0+r][k0+k], swizzled chunks
            #pragma unroll
            for (int cc = 0; cc < 4; ++cc) {
                const int c = ac0 + cc;
                const int k = k0 + c * 8;
                const float4 v0 = *(const float4*)&A[(size_t)(n0 + ar) * 512 + k];
                const float4 v1 = *(const float4*)&A[(size_t)(n0 + ar) * 512 + k + 4];
                f16x8 h;
                h[0]=(f16)v0.x; h[1]=(f16)v0.y; h[2]=(f16)v0.z; h[3]=(f16)v0.w;
                h[4]=(f16)v1.x; h[5]=(f16)v1.y; h[6]=(f16)v1.z; h[7]=(f16)v1.w;
                *(f16x8*)&A_s[ar][(c ^ (ar & 7)) << 3] = h;
            }
            // B_s[jl][k] = (f16)Why[k0+k][j0+jl], swizzled chunks (transposed scatter)
            {
                const int c  = bk >> 3;           // k chunk 0..7
                const int ke = bk & 7;            // element within chunk
                #pragma unroll
                for (int u = 0; u < 8; ++u) {
                    const int jl = bjq * 32 + u * 4;
                    const float4 v = *(const float4*)&Why[(size_t)(k0 + bk) * 512 + j0 + jl];
                    B_s[jl + 0][(((c) ^ ((jl + 0) & 7)) << 3) + ke] = (f16)v.x;
                    B_s[jl + 1][(((c) ^ ((jl + 1) & 7)) << 3) + ke] = (f16)v.y;
                    B_s[jl + 2][(((c) ^ ((jl + 2) & 7)) << 3) + ke] = (f16)v.z;
                    B_s[jl + 3][(((c) ^ ((jl + 3) & 7)) << 3) + ke] = (f16)v.w;
                }
            }
            __syncthreads();
            #pragma unroll
            for (int kc = 0; kc < 8; kc += 4) {
                f16x8 a[4], bfr[4];
                #pragma unroll
                for (int t = 0; t < 4; ++t)
                    a[t] = *(const f16x8*)&A_s[wm * 64 + t * 16 + fr][((kc + q) ^ sw) << 3];
                #pragma unroll
                for (int t = 0; t < 4; ++t)
                    bfr[t] = *(const f16x8*)&B_s[wn * 64 + t * 16 + fr][((kc + q) ^ sw) << 3];
                #pragma unroll
                for (int im = 0; im < 4; ++im)
                    #pragma unroll
                    for (int jn = 0; jn < 4; ++jn)
                        acc[im][jn] = __builtin_amdgcn_mfma_f32_16x16x32_f16(
                            a[im], bfr[jn], acc[im][jn], 0, 0, 0);
            }
        }

        const int r0 = q * 4, c = fr;
        #pragma unroll
        for (int jn = 0; jn < 4; ++jn) {
            const int j = j0 + wn * 64 + jn * 16 + c;
            #pragma unroll
            for (int im = 0; im < 4; ++im)
                #pragma unroll
                for (int r = 0; r < 4; ++r) {
                    const int n = n0 + wm * 64 + im * 16 + r0 + r;
                    Cp[(size_t)n * KDIM + j] =
                        (f16)(acc[im][jn][r] + Cadd[(size_t)n * KDIM + j]);
                }
        }
    }
}

extern "C" void kernel_launch(void* const* d_in, const int* in_sizes, int n_in,
                              void* d_out, int out_size, void* d_ws, size_t ws_size,
                              hipStream_t stream)
{
    (void)in_sizes; (void)n_in; (void)out_size; (void)ws_size;

    const float* xs     = (const float*)d_in[0];
    const float* W_xh0  = (const float*)d_in[1];
    const float* b_xh0  = (const float*)d_in[2];
    /* d_in[3] = W_hh0 unused (hs==0; only its bias matters) */
    const float* b_hh0  = (const float*)d_in[4];
    const float* W_hy0  = (const float*)d_in[5];
    const float* b_hy0  = (const float*)d_in[6];
    const float* W_xh_h = (const float*)d_in[7];
    const float* b_xh_h = (const float*)d_in[8];
    const float* W_hh_h = (const float*)d_in[9];
    const float* b_hh_h = (const float*)d_in[10];
    const float* W_hy_h = (const float*)d_in[11];
    const float* b_hy_h = (const float*)d_in[12];

    f16*   Wp   = (f16*)d_ws;                  // [4][WSZ] phase weights
    float* bias = (float*)(Wp + 4 * WSZ);      // [4][512]

    // ONE prep kernel (cvt + biases + both folds from raw fp32), then the chain.
    prep_mega<<<305, dim3(256), 0, stream>>>(W_xh0, W_xh_h, W_hh_h, W_hy0, W_hy_h,
                                             b_xh0, b_hh0, b_xh_h, b_hh_h,
                                             b_hy0, b_hy_h, Wp, bias);
    // fused chain: 256 blocks x 512 threads (proven geometry), pipelined inner loop
    chain_kernel<<<256, dim3(512), 0, stream>>>(xs, Wp, bias, (float*)d_out);
}

// Round 8
// 241.899 us; speedup vs baseline: 1.1765x; 1.1765x over previous
//
#include <hip/hip_runtime.h>
#include <hip/hip_fp16.h>

typedef _Float16 f16;
typedef f16 f16x4 __attribute__((ext_vector_type(4)));
typedef f16 f16x8 __attribute__((ext_vector_type(8)));
typedef float f32x4 __attribute__((ext_vector_type(4)));

#define NTOK 32768   // B*S
#define KDIM 512
#define SLEN 4096
#define BATCH 8
#define WSZ  262144  // 512*512

// rcp-based tanh: (1-t)*rcp(1+t) instead of fdiv (~1/3 the VALU ops).
// v_rcp_f32 is ~1 ULP(22b) — invisible after the f16 round of the h write-back
// (verified round 7: absmax unchanged at 0.0039).
__device__ __forceinline__ float fast_tanh(float x) {
    float ax = fabsf(x);
    float t = __expf(-2.0f * ax);
    float r = (1.0f - t) * __builtin_amdgcn_rcpf(1.0f + t);
    return copysignf(r, x);
}

// ---------------- chain inner-loop helpers: 2-deep pipelined kt loop ----------------
// (round-5 form EXACTLY — deeper hf-pipelining and full unroll regressed in r7
//  via block phase-drift -> L2 thrash: FETCH 45->112 MB)
__device__ __forceinline__ void load_wf(f16x8 (&wf)[4], const f16* __restrict__ wp,
                                        int j0w, int fr, int col)
{
    #pragma unroll
    for (int jt = 0; jt < 4; ++jt)
        wf[jt] = *(const f16x8*)&wp[(size_t)(j0w + jt * 16 + fr) * KDIM + col];
}

__device__ __forceinline__ void half_mt(f32x4 (&acc)[4][8], const f16 (*hbuf)[512],
                                        const f16x8 (&wf)[4], int kt, int fr, int q, int mt0)
{
    f16x8 hf[4];
    #pragma unroll
    for (int i = 0; i < 4; ++i) {
        const int m = (mt0 + i) * 16 + fr;
        const int c = (kt * 4 + q) ^ (m & 7);
        hf[i] = *(const f16x8*)&hbuf[m][c << 3];
    }
    __builtin_amdgcn_s_setprio(1);
    #pragma unroll
    for (int jt = 0; jt < 4; ++jt)
        #pragma unroll
        for (int i = 0; i < 4; ++i)
            acc[jt][mt0 + i] = __builtin_amdgcn_mfma_f32_16x16x32_f16(
                wf[jt], hf[i], acc[jt][mt0 + i], 0, 0, 0);
    __builtin_amdgcn_s_setprio(0);
}

// kt loop with named ping/pong weight buffers: weights for kt+1 / kt+2 are issued
// BEFORE the MFMAs that consume kt -> global-load latency hides under matrix work.
// The kt=14 bottom prefetch targets kt=16 (dead, but lands in valid workspace:
// <= ~2 KB past this phase's 512 KB, inside Wp[ph+1] or the bias array).
__device__ __forceinline__ void gemm_ktloop(f32x4 (&acc)[4][8], const f16 (*hbuf)[512],
                                            const f16* __restrict__ wp, f16x8 (&wfA)[4],
                                            int j0w, int fr, int q)
{
    f16x8 wfB[4];
    for (int kt = 0; kt < 16; kt += 2) {
        load_wf(wfB, wp, j0w, fr, (kt + 1) * 32 + q * 8);
        half_mt(acc, hbuf, wfA, kt, fr, q, 0);
        half_mt(acc, hbuf, wfA, kt, fr, q, 4);
        load_wf(wfA, wp, j0w, fr, (kt + 2) * 32 + q * 8);
        half_mt(acc, hbuf, wfB, kt + 1, fr, q, 0);
        half_mt(acc, hbuf, wfB, kt + 1, fr, q, 4);
    }
}

// =====================  fused 4-phase chain (proven geometry)  =====================
// Each block owns 128 tokens. LDS holds h (or X) as [token 128][feature 512] f16,
// XOR-swizzled in 16B chunks: element (m, f) lives at m*512 + ((f>>3 ^ (m&7))<<3) + (f&7).
// GEOMETRY AND SCHEDULE ARE LOAD-BEARING: 128 tokens/block, 8 waves, 64 feat/wave,
// rolled kt loop, 2-deep W prefetch only. Deviations (r3: 64 tok/block, r6: 16
// waves, r7: hf-prefetch + full unroll) all exploded HBM traffic 2.5-4x via
// block phase-drift -> per-XCD L2 thrash.
__global__ __launch_bounds__(512, 2)
void chain_kernel(const float* __restrict__ xs,
                  const f16*  __restrict__ Wp,    // [4][512*512] f16 row-major [j][k]
                  const float* __restrict__ bias, // [4][512] fp32
                  float* __restrict__ out)        // y2 [S,B,512] then hs [8*512]
{
    __shared__ f16 hbuf[128][512];   // 128 KB

    const int tid  = threadIdx.x;
    const int bid  = blockIdx.x;
    const int n0   = bid * 128;
    const int lane = tid & 63;
    const int wave = tid >> 6;       // 0..7: wave owns features [wave*64, +64)
    const int fr   = lane & 15;      // token within 16-tile (D^T col)
    const int q    = lane >> 4;      // 0..3
    const int j0w  = wave * 64;

    // ---- stage X tile: fp32 -> f16 into hbuf (swizzled) ----
    {
        const int tk = tid >> 2;                 // 0..127
        const int cq = tid & 3;                  // 0..3
        const float* __restrict__ src = &xs[(size_t)(n0 + tk) * KDIM];
        #pragma unroll
        for (int kt = 0; kt < 16; ++kt) {
            const int k = kt * 32 + cq * 8;
            const float4 v0 = *(const float4*)&src[k];
            const float4 v1 = *(const float4*)&src[k + 4];
            f16x8 h;
            h[0]=(f16)v0.x; h[1]=(f16)v0.y; h[2]=(f16)v0.z; h[3]=(f16)v0.w;
            h[4]=(f16)v1.x; h[5]=(f16)v1.y; h[6]=(f16)v1.z; h[7]=(f16)v1.w;
            const int c = (k >> 3) ^ (tk & 7);
            *(f16x8*)&hbuf[tk][c << 3] = h;
        }
    }

    f32x4 acc[4][8];   // [jt][mt] : 128 AGPRs

    // ---- phases 0..2: h = tanh(h_prev @ W^T + b), in-place in LDS ----
    for (int ph = 0; ph < 3; ++ph) {
        const f16*   __restrict__ wp = Wp + (size_t)ph * WSZ;
        const float* __restrict__ bp = bias + ph * KDIM;

        f16x8 wfA[4];
        load_wf(wfA, wp, j0w, fr, q * 8);   // kt=0 prefetch, before the barrier

        f32x4 bv[4];
        #pragma unroll
        for (int jt = 0; jt < 4; ++jt)
            bv[jt] = *(const f32x4*)&bp[j0w + jt * 16 + q * 4];
        #pragma unroll
        for (int jt = 0; jt < 4; ++jt)
            #pragma unroll
            for (int mt = 0; mt < 8; ++mt)
                acc[jt][mt] = bv[jt];

        __syncthreads();   // h (or X) writes visible before reads

        gemm_ktloop(acc, hbuf, wp, wfA, j0w, fr, q);

        __syncthreads();   // all reads done before overwrite

        #pragma unroll
        for (int jt = 0; jt < 4; ++jt) {
            const int j0f  = j0w + jt * 16 + q * 4;   // 4 consecutive features
            const int c    = j0f >> 3;
            const int half = j0f & 7;                 // 0 or 4
            #pragma unroll
            for (int mt = 0; mt < 8; ++mt) {
                const int m = mt * 16 + fr;
                f16x4 hv;
                hv[0] = (f16)fast_tanh(acc[jt][mt][0]);
                hv[1] = (f16)fast_tanh(acc[jt][mt][1]);
                hv[2] = (f16)fast_tanh(acc[jt][mt][2]);
                hv[3] = (f16)fast_tanh(acc[jt][mt][3]);
                *(f16x4*)&hbuf[m][((c ^ (m & 7)) << 3) + half] = hv;
            }
        }
    }

    // ---- phase 3: y2 = h2 @ W_hy1^T + b -> global (D^T layout matches [s,b,j]) ----
    {
        const f16*   __restrict__ wp = Wp + (size_t)3 * WSZ;
        const float* __restrict__ bp = bias + 3 * KDIM;

        f16x8 wfA[4];
        load_wf(wfA, wp, j0w, fr, q * 8);   // kt=0 prefetch

        f32x4 bv[4];
        #pragma unroll
        for (int jt = 0; jt < 4; ++jt)
            bv[jt] = *(const f32x4*)&bp[j0w + jt * 16 + q * 4];
        #pragma unroll
        for (int jt = 0; jt < 4; ++jt)
            #pragma unroll
            for (int mt = 0; mt < 8; ++mt)
                acc[jt][mt] = bv[jt];

        __syncthreads();   // h2 writes visible

        // hs_final: blocks holding token s==4095 (bid = 32b+31, local token 127)
        if ((bid & 31) == 31) {
            const int f = tid;                      // feature 0..511
            const int c = (f >> 3) ^ 7;             // m=127 -> m&7 = 7
            out[(size_t)SLEN * BATCH * KDIM + (size_t)(bid >> 5) * KDIM + f] =
                (float)hbuf[127][(c << 3) + (f & 7)];
        }

        gemm_ktloop(acc, hbuf, wp, wfA, j0w, fr, q);

        #pragma unroll
        for (int jt = 0; jt < 4; ++jt) {
            const int j = j0w + jt * 16 + q * 4;
            #pragma unroll
            for (int mt = 0; mt < 8; ++mt) {
                const int n  = n0 + mt * 16 + fr;
                const int s  = n & (SLEN - 1);
                const int bb = n >> 12;
                *(f32x4*)&out[(size_t)(s * BATCH + bb) * KDIM + j] = acc[jt][mt];
            }
        }
    }
}

// ============================================================================
// prep_mega: ONE kernel for everything before the chain (unchanged, verified).
//   blocks [0,128)    : cvt W_xh0 (fp32->f16)     -> Wp[0]
//   blocks [128,256)  : cvt W_hy_h[1] (fp32->f16) -> Wp[3]
//   blocks [256,272)  : bias matvec rows 1..2
//   block  272        : trivial bias rows 0,3
//   blocks [273,305)  : fold GEMMs FROM RAW fp32:
//       Wp[1+li] = W_hh_h[li] + W_xh_h[li] @ W_hy_prev   (f16 out)
// ============================================================================
__device__ __forceinline__ void cvt2048(const float* __restrict__ src, f16* __restrict__ dst, int t)
{
    const float4 v0 = *(const float4*)&src[(size_t)t * 8];
    const float4 v1 = *(const float4*)&src[(size_t)t * 8 + 4];
    f16x8 h;
    h[0]=(f16)v0.x; h[1]=(f16)v0.y; h[2]=(f16)v0.z; h[3]=(f16)v0.w;
    h[4]=(f16)v1.x; h[5]=(f16)v1.y; h[6]=(f16)v1.z; h[7]=(f16)v1.w;
    *(f16x8*)&dst[(size_t)t * 8] = h;
}

__global__ __launch_bounds__(256)
void prep_mega(const float* __restrict__ W_xh0, const float* __restrict__ W_xh_h,
               const float* __restrict__ W_hh_h, const float* __restrict__ W_hy0,
               const float* __restrict__ W_hy_h,
               const float* __restrict__ b_xh0, const float* __restrict__ b_hh0,
               const float* __restrict__ b_xh_h, const float* __restrict__ b_hh_h,
               const float* __restrict__ b_hy0, const float* __restrict__ b_hy_h,
               f16* __restrict__ Wp, float* __restrict__ bias)
{
    __shared__ f16 A_s[128][64];   // 16 KB
    __shared__ f16 B_s[128][64];   // 16 KB

    const int b = blockIdx.x, tid = threadIdx.x;
    const int lane = tid & 63, wave = tid >> 6;

    if (b < 128) { cvt2048(W_xh0, Wp, b * 256 + tid); return; }
    if (b < 256) { cvt2048(W_hy_h + WSZ, Wp + 3 * WSZ, (b - 128) * 256 + tid); return; }

    if (b < 272) {
        // bias rows 1..2: bias[1+li][j] = b_hh + b_xh + W_xh_h[li][j,:] . b_hy_prev
        const int bb = b - 256;                   // 0..15
        const int li = bb >> 3;                   // 0..1
        const int j0 = (bb & 7) * 64 + wave * 16;
        const float* __restrict__ W  = W_xh_h + (size_t)li * WSZ;
        const float* __restrict__ bh = li ? b_hy_h : b_hy0;
        const float4 h0 = *(const float4*)&bh[lane * 8];
        const float4 h1 = *(const float4*)&bh[lane * 8 + 4];
        for (int jj = 0; jj < 16; ++jj) {
            const int j = j0 + jj;
            const float4 w0 = *(const float4*)&W[(size_t)j * 512 + lane * 8];
            const float4 w1 = *(const float4*)&W[(size_t)j * 512 + lane * 8 + 4];
            float s = w0.x*h0.x + w0.y*h0.y + w0.z*h0.z + w0.w*h0.w
                    + w1.x*h1.x + w1.y*h1.y + w1.z*h1.z + w1.w*h1.w;
            #pragma unroll
            for (int off = 32; off; off >>= 1) s += __shfl_xor(s, off, 64);
            if (lane == 0)
                bias[(1 + li) * KDIM + j] =
                    b_hh_h[li * KDIM + j] + b_xh_h[li * KDIM + j] + s;
        }
        return;
    }

    if (b == 272) {
        // bias rows 0 and 3 (trivial elementwise), 256 threads x 2 j
        #pragma unroll
        for (int u = 0; u < 2; ++u) {
            const int j = u * 256 + tid;
            bias[j] = b_xh0[j] + b_hh0[j];
            bias[3 * KDIM + j] = b_hy_h[KDIM + j];
        }
        return;
    }

    // ---- fold GEMM from raw fp32: Wp[1+li] = W_hh_h[li] + W_xh_h[li] @ W_hy_prev ----
    {
        const int fb   = b - 273;                 // 0..31
        const int fold = fb >> 4;                 // 0..1 (= li)
        const int bid  = fb & 15;
        const float* __restrict__ A    = W_xh_h + (size_t)fold * WSZ;  // [n][k] fp32
        const float* __restrict__ Why  = fold ? W_hy_h : W_hy0;        // [k][j] fp32
        const float* __restrict__ Cadd = W_hh_h + (size_t)fold * WSZ;
        f16*         __restrict__ Cp   = Wp + WSZ + (size_t)fold * WSZ;

        const int n0 = (bid >> 2) * 128;
        const int j0 = (bid & 3) * 128;

        const int wm = wave >> 1, wn = wave & 1;
        const int fr = lane & 15, q = lane >> 4, sw = fr & 7;

        // staging thread mapping
        const int ar  = tid >> 1;                 // row 0..127 (A stage)
        const int ac0 = (tid & 1) * 4;            // chunk base 0 or 4
        const int bk  = tid >> 2;                 // k 0..63 (B stage)
        const int bjq = tid & 3;                  // j quarter (32 j each)

        f32x4 acc[4][4] = {};

        for (int kt = 0; kt < 8; ++kt) {
            const int k0 = kt * 64;
            __syncthreads();   // previous reads done before overwrite
            // A_s[r][k] = (f16)A[n0+r][k0+k], swizzled chunks
            #pragma unroll
            for (int cc = 0; cc < 4; ++cc) {
                const int c = ac0 + cc;
                const int k = k0 + c * 8;
                const float4 v0 = *(const float4*)&A[(size_t)(n0 + ar) * 512 + k];
                const float4 v1 = *(const float4*)&A[(size_t)(n0 + ar) * 512 + k + 4];
                f16x8 h;
                h[0]=(f16)v0.x; h[1]=(f16)v0.y; h[2]=(f16)v0.z; h[3]=(f16)v0.w;
                h[4]=(f16)v1.x; h[5]=(f16)v1.y; h[6]=(f16)v1.z; h[7]=(f16)v1.w;
                *(f16x8*)&A_s[ar][(c ^ (ar & 7)) << 3] = h;
            }
            // B_s[jl][k] = (f16)Why[k0+k][j0+jl], swizzled chunks (transposed scatter)
            {
                const int c  = bk >> 3;           // k chunk 0..7
                const int ke = bk & 7;            // element within chunk
                #pragma unroll
                for (int u = 0; u < 8; ++u) {
                    const int jl = bjq * 32 + u * 4;
                    const float4 v = *(const float4*)&Why[(size_t)(k0 + bk) * 512 + j0 + jl];
                    B_s[jl + 0][(((c) ^ ((jl + 0) & 7)) << 3) + ke] = (f16)v.x;
                    B_s[jl + 1][(((c) ^ ((jl + 1) & 7)) << 3) + ke] = (f16)v.y;
                    B_s[jl + 2][(((c) ^ ((jl + 2) & 7)) << 3) + ke] = (f16)v.z;
                    B_s[jl + 3][(((c) ^ ((jl + 3) & 7)) << 3) + ke] = (f16)v.w;
                }
            }
            __syncthreads();
            #pragma unroll
            for (int kc = 0; kc < 8; kc += 4) {
                f16x8 a[4], bfr[4];
                #pragma unroll
                for (int t = 0; t < 4; ++t)
                    a[t] = *(const f16x8*)&A_s[wm * 64 + t * 16 + fr][((kc + q) ^ sw) << 3];
                #pragma unroll
                for (int t = 0; t < 4; ++t)
                    bfr[t] = *(const f16x8*)&B_s[wn * 64 + t * 16 + fr][((kc + q) ^ sw) << 3];
                #pragma unroll
                for (int im = 0; im < 4; ++im)
                    #pragma unroll
                    for (int jn = 0; jn < 4; ++jn)
                        acc[im][jn] = __builtin_amdgcn_mfma_f32_16x16x32_f16(
                            a[im], bfr[jn], acc[im][jn], 0, 0, 0);
            }
        }

        const int r0 = q * 4, c = fr;
        #pragma unroll
        for (int jn = 0; jn < 4; ++jn) {
            const int j = j0 + wn * 64 + jn * 16 + c;
            #pragma unroll
            for (int im = 0; im < 4; ++im)
                #pragma unroll
                for (int r = 0; r < 4; ++r) {
                    const int n = n0 + wm * 64 + im * 16 + r0 + r;
                    Cp[(size_t)n * KDIM + j] =
                        (f16)(acc[im][jn][r] + Cadd[(size_t)n * KDIM + j]);
                }
        }
    }
}

extern "C" void kernel_launch(void* const* d_in, const int* in_sizes, int n_in,
                              void* d_out, int out_size, void* d_ws, size_t ws_size,
                              hipStream_t stream)
{
    (void)in_sizes; (void)n_in; (void)out_size; (void)ws_size;

    const float* xs     = (const float*)d_in[0];
    const float* W_xh0  = (const float*)d_in[1];
    const float* b_xh0  = (const float*)d_in[2];
    /* d_in[3] = W_hh0 unused (hs==0; only its bias matters) */
    const float* b_hh0  = (const float*)d_in[4];
    const float* W_hy0  = (const float*)d_in[5];
    const float* b_hy0  = (const float*)d_in[6];
    const float* W_xh_h = (const float*)d_in[7];
    const float* b_xh_h = (const float*)d_in[8];
    const float* W_hh_h = (const float*)d_in[9];
    const float* b_hh_h = (const float*)d_in[10];
    const float* W_hy_h = (const float*)d_in[11];
    const float* b_hy_h = (const float*)d_in[12];

    f16*   Wp   = (f16*)d_ws;                  // [4][WSZ] phase weights
    float* bias = (float*)(Wp + 4 * WSZ);      // [4][512]

    // ONE prep kernel (cvt + biases + both folds from raw fp32), then the chain.
    prep_mega<<<305, dim3(256), 0, stream>>>(W_xh0, W_xh_h, W_hh_h, W_hy0, W_hy_h,
                                             b_xh0, b_hh0, b_xh_h, b_hh_h,
                                             b_hy0, b_hy_h, Wp, bias);
    // fused chain: 256 blocks x 512 threads (round-5 proven schedule + rcp-tanh)
    chain_kernel<<<256, dim3(512), 0, stream>>>(xs, Wp, bias, (float*)d_out);
}

// Round 9
// 239.976 us; speedup vs baseline: 1.1859x; 1.0080x over previous
//
#include <hip/hip_runtime.h>
#include <hip/hip_fp16.h>

typedef _Float16 f16;
typedef f16 f16x4 __attribute__((ext_vector_type(4)));
typedef f16 f16x8 __attribute__((ext_vector_type(8)));
typedef float f32x4 __attribute__((ext_vector_type(4)));

#define NTOK 32768   // B*S
#define KDIM 512
#define SLEN 4096
#define BATCH 8
#define WSZ  262144  // 512*512

// rcp-based tanh: (1-t)*rcp(1+t) instead of fdiv (~1/3 the VALU ops).
// v_rcp_f32 is ~1 ULP(22b) — invisible after the f16 round of the h write-back
// (verified round 7/8: absmax unchanged at 0.0039).
__device__ __forceinline__ float fast_tanh(float x) {
    float ax = fabsf(x);
    float t = __expf(-2.0f * ax);
    float r = (1.0f - t) * __builtin_amdgcn_rcpf(1.0f + t);
    return copysignf(r, x);
}

// ---------------- chain inner-loop helpers: 2-deep pipelined kt loop ----------------
// (round-5 form EXACTLY — deeper hf-pipelining and full unroll regressed in r7
//  via block phase-drift -> L2 thrash: FETCH 45->112 MB)
__device__ __forceinline__ void load_wf(f16x8 (&wf)[4], const f16* __restrict__ wp,
                                        int j0w, int fr, int col)
{
    #pragma unroll
    for (int jt = 0; jt < 4; ++jt)
        wf[jt] = *(const f16x8*)&wp[(size_t)(j0w + jt * 16 + fr) * KDIM + col];
}

__device__ __forceinline__ void half_mt(f32x4 (&acc)[4][8], const f16 (*hbuf)[512],
                                        const f16x8 (&wf)[4], int kt, int fr, int q, int mt0)
{
    f16x8 hf[4];
    #pragma unroll
    for (int i = 0; i < 4; ++i) {
        const int m = (mt0 + i) * 16 + fr;
        const int c = (kt * 4 + q) ^ (m & 7);
        hf[i] = *(const f16x8*)&hbuf[m][c << 3];
    }
    __builtin_amdgcn_s_setprio(1);
    #pragma unroll
    for (int jt = 0; jt < 4; ++jt)
        #pragma unroll
        for (int i = 0; i < 4; ++i)
            acc[jt][mt0 + i] = __builtin_amdgcn_mfma_f32_16x16x32_f16(
                wf[jt], hf[i], acc[jt][mt0 + i], 0, 0, 0);
    __builtin_amdgcn_s_setprio(0);
}

// kt loop with named ping/pong weight buffers: weights for kt+1 / kt+2 are issued
// BEFORE the MFMAs that consume kt -> global-load latency hides under matrix work.
// The kt=14 bottom prefetch targets kt=16 (dead, but lands in valid workspace:
// <= ~2 KB past this phase's 512 KB, inside Wp[ph+1] or the bias array).
__device__ __forceinline__ void gemm_ktloop(f32x4 (&acc)[4][8], const f16 (*hbuf)[512],
                                            const f16* __restrict__ wp, f16x8 (&wfA)[4],
                                            int j0w, int fr, int q)
{
    f16x8 wfB[4];
    for (int kt = 0; kt < 16; kt += 2) {
        load_wf(wfB, wp, j0w, fr, (kt + 1) * 32 + q * 8);
        half_mt(acc, hbuf, wfA, kt, fr, q, 0);
        half_mt(acc, hbuf, wfA, kt, fr, q, 4);
        load_wf(wfA, wp, j0w, fr, (kt + 2) * 32 + q * 8);
        half_mt(acc, hbuf, wfB, kt + 1, fr, q, 0);
        half_mt(acc, hbuf, wfB, kt + 1, fr, q, 4);
    }
}

// =====================  fused 4-phase chain (proven geometry)  =====================
// Each block owns 128 tokens. LDS holds h (or X) as [token 128][feature 512] f16,
// XOR-swizzled in 16B chunks: element (m, f) lives at m*512 + ((f>>3 ^ (m&7))<<3) + (f&7).
// GEOMETRY AND SCHEDULE ARE LOAD-BEARING: 128 tokens/block, 8 waves, 64 feat/wave,
// rolled kt loop, 2-deep W prefetch only. Deviations (r3: 64 tok/block, r6: 16
// waves, r7: hf-prefetch + full unroll) all exploded HBM traffic 2.5-4x via
// block phase-drift -> per-XCD L2 thrash.
// Serialized-pipe regime (r8 calibration: rcp-tanh saved VALU cycles 1:1 in
// wall clock) -> epilogue tanh is computed BEFORE the barrier (register-only),
// only the ds_writes wait.
__global__ __launch_bounds__(512, 2)
void chain_kernel(const float* __restrict__ xs,
                  const f16*  __restrict__ Wp,    // [4][512*512] f16 row-major [j][k]
                  const float* __restrict__ bias, // [4][512] fp32
                  float* __restrict__ out)        // y2 [S,B,512] then hs [8*512]
{
    __shared__ f16 hbuf[128][512];   // 128 KB

    const int tid  = threadIdx.x;
    const int bid  = blockIdx.x;
    const int n0   = bid * 128;
    const int lane = tid & 63;
    const int wave = tid >> 6;       // 0..7: wave owns features [wave*64, +64)
    const int fr   = lane & 15;      // token within 16-tile (D^T col)
    const int q    = lane >> 4;      // 0..3
    const int j0w  = wave * 64;

    // ---- stage X tile: fp32 -> f16 into hbuf (swizzled) ----
    {
        const int tk = tid >> 2;                 // 0..127
        const int cq = tid & 3;                  // 0..3
        const float* __restrict__ src = &xs[(size_t)(n0 + tk) * KDIM];
        #pragma unroll
        for (int kt = 0; kt < 16; ++kt) {
            const int k = kt * 32 + cq * 8;
            const float4 v0 = *(const float4*)&src[k];
            const float4 v1 = *(const float4*)&src[k + 4];
            f16x8 h;
            h[0]=(f16)v0.x; h[1]=(f16)v0.y; h[2]=(f16)v0.z; h[3]=(f16)v0.w;
            h[4]=(f16)v1.x; h[5]=(f16)v1.y; h[6]=(f16)v1.z; h[7]=(f16)v1.w;
            const int c = (k >> 3) ^ (tk & 7);
            *(f16x8*)&hbuf[tk][c << 3] = h;
        }
    }

    f32x4 acc[4][8];   // [jt][mt] : 128 AGPRs

    // ---- phases 0..2: h = tanh(h_prev @ W^T + b), in-place in LDS ----
    for (int ph = 0; ph < 3; ++ph) {
        const f16*   __restrict__ wp = Wp + (size_t)ph * WSZ;
        const float* __restrict__ bp = bias + ph * KDIM;

        f16x8 wfA[4];
        load_wf(wfA, wp, j0w, fr, q * 8);   // kt=0 prefetch, before the barrier

        f32x4 bv[4];
        #pragma unroll
        for (int jt = 0; jt < 4; ++jt)
            bv[jt] = *(const f32x4*)&bp[j0w + jt * 16 + q * 4];
        #pragma unroll
        for (int jt = 0; jt < 4; ++jt)
            #pragma unroll
            for (int mt = 0; mt < 8; ++mt)
                acc[jt][mt] = bv[jt];

        __syncthreads();   // h (or X) writes visible before reads

        gemm_ktloop(acc, hbuf, wp, wfA, j0w, fr, q);

        // tanh + f16 pack on REGISTERS before the barrier: overlaps other waves'
        // kt-loop tail / barrier wait (serialized-pipe regime, r8 calibration)
        f16x4 hv[4][8];
        #pragma unroll
        for (int jt = 0; jt < 4; ++jt)
            #pragma unroll
            for (int mt = 0; mt < 8; ++mt) {
                hv[jt][mt][0] = (f16)fast_tanh(acc[jt][mt][0]);
                hv[jt][mt][1] = (f16)fast_tanh(acc[jt][mt][1]);
                hv[jt][mt][2] = (f16)fast_tanh(acc[jt][mt][2]);
                hv[jt][mt][3] = (f16)fast_tanh(acc[jt][mt][3]);
            }

        __syncthreads();   // all reads done before overwrite

        #pragma unroll
        for (int jt = 0; jt < 4; ++jt) {
            const int j0f  = j0w + jt * 16 + q * 4;   // 4 consecutive features
            const int c    = j0f >> 3;
            const int half = j0f & 7;                 // 0 or 4
            #pragma unroll
            for (int mt = 0; mt < 8; ++mt) {
                const int m = mt * 16 + fr;
                *(f16x4*)&hbuf[m][((c ^ (m & 7)) << 3) + half] = hv[jt][mt];
            }
        }
    }

    // ---- phase 3: y2 = h2 @ W_hy1^T + b -> global (D^T layout matches [s,b,j]) ----
    {
        const f16*   __restrict__ wp = Wp + (size_t)3 * WSZ;
        const float* __restrict__ bp = bias + 3 * KDIM;

        f16x8 wfA[4];
        load_wf(wfA, wp, j0w, fr, q * 8);   // kt=0 prefetch

        f32x4 bv[4];
        #pragma unroll
        for (int jt = 0; jt < 4; ++jt)
            bv[jt] = *(const f32x4*)&bp[j0w + jt * 16 + q * 4];
        #pragma unroll
        for (int jt = 0; jt < 4; ++jt)
            #pragma unroll
            for (int mt = 0; mt < 8; ++mt)
                acc[jt][mt] = bv[jt];

        __syncthreads();   // h2 writes visible

        // hs_final: blocks holding token s==4095 (bid = 32b+31, local token 127)
        if ((bid & 31) == 31) {
            const int f = tid;                      // feature 0..511
            const int c = (f >> 3) ^ 7;             // m=127 -> m&7 = 7
            out[(size_t)SLEN * BATCH * KDIM + (size_t)(bid >> 5) * KDIM + f] =
                (float)hbuf[127][(c << 3) + (f & 7)];
        }

        gemm_ktloop(acc, hbuf, wp, wfA, j0w, fr, q);

        #pragma unroll
        for (int jt = 0; jt < 4; ++jt) {
            const int j = j0w + jt * 16 + q * 4;
            #pragma unroll
            for (int mt = 0; mt < 8; ++mt) {
                const int n  = n0 + mt * 16 + fr;
                const int s  = n & (SLEN - 1);
                const int bb = n >> 12;
                *(f32x4*)&out[(size_t)(s * BATCH + bb) * KDIM + j] = acc[jt][mt];
            }
        }
    }
}

// ============================================================================
// prep_mega: ONE kernel for everything before the chain (unchanged, verified).
//   blocks [0,128)    : cvt W_xh0 (fp32->f16)     -> Wp[0]
//   blocks [128,256)  : cvt W_hy_h[1] (fp32->f16) -> Wp[3]
//   blocks [256,272)  : bias matvec rows 1..2
//   block  272        : trivial bias rows 0,3
//   blocks [273,305)  : fold GEMMs FROM RAW fp32:
//       Wp[1+li] = W_hh_h[li] + W_xh_h[li] @ W_hy_prev   (f16 out)
// ============================================================================
__device__ __forceinline__ void cvt2048(const float* __restrict__ src, f16* __restrict__ dst, int t)
{
    const float4 v0 = *(const float4*)&src[(size_t)t * 8];
    const float4 v1 = *(const float4*)&src[(size_t)t * 8 + 4];
    f16x8 h;
    h[0]=(f16)v0.x; h[1]=(f16)v0.y; h[2]=(f16)v0.z; h[3]=(f16)v0.w;
    h[4]=(f16)v1.x; h[5]=(f16)v1.y; h[6]=(f16)v1.z; h[7]=(f16)v1.w;
    *(f16x8*)&dst[(size_t)t * 8] = h;
}

__global__ __launch_bounds__(256)
void prep_mega(const float* __restrict__ W_xh0, const float* __restrict__ W_xh_h,
               const float* __restrict__ W_hh_h, const float* __restrict__ W_hy0,
               const float* __restrict__ W_hy_h,
               const float* __restrict__ b_xh0, const float* __restrict__ b_hh0,
               const float* __restrict__ b_xh_h, const float* __restrict__ b_hh_h,
               const float* __restrict__ b_hy0, const float* __restrict__ b_hy_h,
               f16* __restrict__ Wp, float* __restrict__ bias)
{
    __shared__ f16 A_s[128][64];   // 16 KB
    __shared__ f16 B_s[128][64];   // 16 KB

    const int b = blockIdx.x, tid = threadIdx.x;
    const int lane = tid & 63, wave = tid >> 6;

    if (b < 128) { cvt2048(W_xh0, Wp, b * 256 + tid); return; }
    if (b < 256) { cvt2048(W_hy_h + WSZ, Wp + 3 * WSZ, (b - 128) * 256 + tid); return; }

    if (b < 272) {
        // bias rows 1..2: bias[1+li][j] = b_hh + b_xh + W_xh_h[li][j,:] . b_hy_prev
        const int bb = b - 256;                   // 0..15
        const int li = bb >> 3;                   // 0..1
        const int j0 = (bb & 7) * 64 + wave * 16;
        const float* __restrict__ W  = W_xh_h + (size_t)li * WSZ;
        const float* __restrict__ bh = li ? b_hy_h : b_hy0;
        const float4 h0 = *(const float4*)&bh[lane * 8];
        const float4 h1 = *(const float4*)&bh[lane * 8 + 4];
        for (int jj = 0; jj < 16; ++jj) {
            const int j = j0 + jj;
            const float4 w0 = *(const float4*)&W[(size_t)j * 512 + lane * 8];
            const float4 w1 = *(const float4*)&W[(size_t)j * 512 + lane * 8 + 4];
            float s = w0.x*h0.x + w0.y*h0.y + w0.z*h0.z + w0.w*h0.w
                    + w1.x*h1.x + w1.y*h1.y + w1.z*h1.z + w1.w*h1.w;
            #pragma unroll
            for (int off = 32; off; off >>= 1) s += __shfl_xor(s, off, 64);
            if (lane == 0)
                bias[(1 + li) * KDIM + j] =
                    b_hh_h[li * KDIM + j] + b_xh_h[li * KDIM + j] + s;
        }
        return;
    }

    if (b == 272) {
        // bias rows 0 and 3 (trivial elementwise), 256 threads x 2 j
        #pragma unroll
        for (int u = 0; u < 2; ++u) {
            const int j = u * 256 + tid;
            bias[j] = b_xh0[j] + b_hh0[j];
            bias[3 * KDIM + j] = b_hy_h[KDIM + j];
        }
        return;
    }

    // ---- fold GEMM from raw fp32: Wp[1+li] = W_hh_h[li] + W_xh_h[li] @ W_hy_prev ----
    {
        const int fb   = b - 273;                 // 0..31
        const int fold = fb >> 4;                 // 0..1 (= li)
        const int bid  = fb & 15;
        const float* __restrict__ A    = W_xh_h + (size_t)fold * WSZ;  // [n][k] fp32
        const float* __restrict__ Why  = fold ? W_hy_h : W_hy0;        // [k][j] fp32
        const float* __restrict__ Cadd = W_hh_h + (size_t)fold * WSZ;
        f16*         __restrict__ Cp   = Wp + WSZ + (size_t)fold * WSZ;

        const int n0 = (bid >> 2) * 128;
        const int j0 = (bid & 3) * 128;

        const int wm = wave >> 1, wn = wave & 1;
        const int fr = lane & 15, q = lane >> 4, sw = fr & 7;

        // staging thread mapping
        const int ar  = tid >> 1;                 // row 0..127 (A stage)
        const int ac0 = (tid & 1) * 4;            // chunk base 0 or 4
        const int bk  = tid >> 2;                 // k 0..63 (B stage)
        const int bjq = tid & 3;                  // j quarter (32 j each)

        f32x4 acc[4][4] = {};

        for (int kt = 0; kt < 8; ++kt) {
            const int k0 = kt * 64;
            __syncthreads();   // previous reads done before overwrite
            // A_s[r][k] = (f16)A[n0+r][k0+k], swizzled chunks
            #pragma unroll
            for (int cc = 0; cc < 4; ++cc) {
                const int c = ac0 + cc;
                const int k = k0 + c * 8;
                const float4 v0 = *(const float4*)&A[(size_t)(n0 + ar) * 512 + k];
                const float4 v1 = *(const float4*)&A[(size_t)(n0 + ar) * 512 + k + 4];
                f16x8 h;
                h[0]=(f16)v0.x; h[1]=(f16)v0.y; h[2]=(f16)v0.z; h[3]=(f16)v0.w;
                h[4]=(f16)v1.x; h[5]=(f16)v1.y; h[6]=(f16)v1.z; h[7]=(f16)v1.w;
                *(f16x8*)&A_s[ar][(c ^ (ar & 7)) << 3] = h;
            }
            // B_s[jl][k] = (f16)Why[k0+k][j0+jl], swizzled chunks (transposed scatter)
            {
                const int c  = bk >> 3;           // k chunk 0..7
                const int ke = bk & 7;            // element within chunk
                #pragma unroll
                for (int u = 0; u < 8; ++u) {
                    const int jl = bjq * 32 + u * 4;
                    const float4 v = *(const float4*)&Why[(size_t)(k0 + bk) * 512 + j0 + jl];
                    B_s[jl + 0][(((c) ^ ((jl + 0) & 7)) << 3) + ke] = (f16)v.x;
                    B_s[jl + 1][(((c) ^ ((jl + 1) & 7)) << 3) + ke] = (f16)v.y;
                    B_s[jl + 2][(((c) ^ ((jl + 2) & 7)) << 3) + ke] = (f16)v.z;
                    B_s[jl + 3][(((c) ^ ((jl + 3) & 7)) << 3) + ke] = (f16)v.w;
                }
            }
            __syncthreads();
            #pragma unroll
            for (int kc = 0; kc < 8; kc += 4) {
                f16x8 a[4], bfr[4];
                #pragma unroll
                for (int t = 0; t < 4; ++t)
                    a[t] = *(const f16x8*)&A_s[wm * 64 + t * 16 + fr][((kc + q) ^ sw) << 3];
                #pragma unroll
                for (int t = 0; t < 4; ++t)
                    bfr[t] = *(const f16x8*)&B_s[wn * 64 + t * 16 + fr][((kc + q) ^ sw) << 3];
                #pragma unroll
                for (int im = 0; im < 4; ++im)
                    #pragma unroll
                    for (int jn = 0; jn < 4; ++jn)
                        acc[im][jn] = __builtin_amdgcn_mfma_f32_16x16x32_f16(
                            a[im], bfr[jn], acc[im][jn], 0, 0, 0);
            }
        }

        const int r0 = q * 4, c = fr;
        #pragma unroll
        for (int jn = 0; jn < 4; ++jn) {
            const int j = j0 + wn * 64 + jn * 16 + c;
            #pragma unroll
            for (int im = 0; im < 4; ++im)
                #pragma unroll
                for (int r = 0; r < 4; ++r) {
                    const int n = n0 + wm * 64 + im * 16 + r0 + r;
                    Cp[(size_t)n * KDIM + j] =
                        (f16)(acc[im][jn][r] + Cadd[(size_t)n * KDIM + j]);
                }
        }
    }
}

extern "C" void kernel_launch(void* const* d_in, const int* in_sizes, int n_in,
                              void* d_out, int out_size, void* d_ws, size_t ws_size,
                              hipStream_t stream)
{
    (void)in_sizes; (void)n_in; (void)out_size; (void)ws_size;

    const float* xs     = (const float*)d_in[0];
    const float* W_xh0  = (const float*)d_in[1];
    const float* b_xh0  = (const float*)d_in[2];
    /* d_in[3] = W_hh0 unused (hs==0; only its bias matters) */
    const float* b_hh0  = (const float*)d_in[4];
    const float* W_hy0  = (const float*)d_in[5];
    const float* b_hy0  = (const float*)d_in[6];
    const float* W_xh_h = (const float*)d_in[7];
    const float* b_xh_h = (const float*)d_in[8];
    const float* W_hh_h = (const float*)d_in[9];
    const float* b_hh_h = (const float*)d_in[10];
    const float* W_hy_h = (const float*)d_in[11];
    const float* b_hy_h = (const float*)d_in[12];

    f16*   Wp   = (f16*)d_ws;                  // [4][WSZ] phase weights
    float* bias = (float*)(Wp + 4 * WSZ);      // [4][512]

    // ONE prep kernel (cvt + biases + both folds from raw fp32), then the chain.
    prep_mega<<<305, dim3(256), 0, stream>>>(W_xh0, W_xh_h, W_hh_h, W_hy0, W_hy_h,
                                             b_xh0, b_hh0, b_xh_h, b_hh_h,
                                             b_hy0, b_hy_h, Wp, bias);
    // fused chain: 256 blocks x 512 threads (r8 schedule + pre-barrier tanh)
    chain_kernel<<<256, dim3(512), 0, stream>>>(xs, Wp, bias, (float*)d_out);
}